// Round 2
// baseline (382.693 us; speedup 1.0000x reference)
//
#include <hip/hip_runtime.h>

#define NN 1024
#define DD 256
#define HH 32
#define SS 64

__device__ __forceinline__ float gelu_f(float x) {
    // jax.nn.gelu approximate=True: 0.5*x*(1+tanh(sqrt(2/pi)*(x+0.044715*x^3)))
    const float c1 = 0.7978845608028654f, c2 = 0.044715f;
    float u = c1 * fmaf(c2 * x * x, x, x);
    float e = __expf(-2.0f * fabsf(u));
    float th = (1.0f - e) / (1.0f + e);   // |th| in [0,1), denom in [1,2] -> safe
    th = copysignf(th, u);
    return 0.5f * x * (1.0f + th);
}

// left = local @ W_left, right = local @ W_right  (fp32 out to workspace)
__global__ __launch_bounds__(64) void proj_kernel(
    const float* __restrict__ local_,
    const float* __restrict__ Wl,
    const float* __restrict__ Wr,
    float* __restrict__ leftF, float* __restrict__ rightF)
{
    __shared__ float row[DD];
    const int i = blockIdx.x, t = threadIdx.x;
    float4 v = ((const float4*)(local_ + (size_t)i * DD))[t];   // 4 f32 per thread
    row[4*t+0] = v.x; row[4*t+1] = v.y; row[4*t+2] = v.z; row[4*t+3] = v.w;
    __syncthreads();
    const int h = t & 31;
    const float* W = (t < 32) ? Wl : Wr;
    float acc = 0.0f;
    #pragma unroll 8
    for (int d = 0; d < DD; ++d) acc = fmaf(row[d], W[d*HH + h], acc);
    float* dst = (t < 32) ? leftF : rightF;
    dst[i*HH + h] = acc;
}

__global__ __launch_bounds__(256) void pair_kernel(
    const float* __restrict__ leftF, const float* __restrict__ rightF,
    const int* __restrict__ resi, const int* __restrict__ chain,
    const int* __restrict__ batch, const int* __restrict__ mask,
    const float* __restrict__ Wrel,
    const float* __restrict__ lnS, const float* __restrict__ lnO,
    const float* __restrict__ Wh, const float* __restrict__ Wout,
    float* __restrict__ out)
{
    __shared__ float4 Wh4[HH * 8];      // Wh4[h*8+q] = W_hidden[h][4q..4q+3]
    __shared__ float hidL[256][36];     // 36-float rows: 16B-aligned, bank-spread
    __shared__ float pmf[256];
    __shared__ float leftL[HH], lnSL[HH], lnOL[HH];

    const int t  = threadIdx.x;
    const int i  = blockIdx.y;
    const int j0 = blockIdx.x * 256;
    const int j  = j0 + t;

    // stage W_hidden -> LDS (4 f32 per thread, 256 threads = 1024 = 32x32)
    ((float4*)Wh4)[t] = ((const float4*)Wh)[t];
    if (t < HH) {
        leftL[t] = leftF[i*HH + t];
        lnSL[t]  = lnS[t];
        lnOL[t]  = lnO[t];
    }
    __syncthreads();

    // ---- phase 1: one pair per thread -> hidden[32] into LDS ----
    const int bi = batch[i], ci = chain[i], ri = resi[i], mi = mask[i];
    const int bj = batch[j], cj = chain[j], rj = resi[j], mj = mask[j];
    const bool sb = (bi == bj);
    const bool sc = sb && (ci == cj);
    const float pm = (sb && (mi != 0) && (mj != 0)) ? 1.0f : 0.0f;

    float pr[HH];
    const float4* rp = (const float4*)(rightF + (size_t)j * HH);
    #pragma unroll
    for (int q = 0; q < 8; ++q) {
        float4 v = rp[q];
        pr[4*q+0] = v.x; pr[4*q+1] = v.y; pr[4*q+2] = v.z; pr[4*q+3] = v.w;
    }
    if (sc) {
        int d = ri - rj; d = d < -32 ? -32 : (d > 32 ? 32 : d);
        const float4* wr = (const float4*)(Wrel + (size_t)(d + 32) * HH);
        #pragma unroll
        for (int q = 0; q < 8; ++q) {
            float4 v = wr[q];
            pr[4*q+0] += v.x; pr[4*q+1] += v.y; pr[4*q+2] += v.z; pr[4*q+3] += v.w;
        }
    }
    float mu = 0.0f;
    #pragma unroll
    for (int h = 0; h < HH; ++h) { pr[h] += leftL[h]; mu += pr[h]; }
    mu *= (1.0f / HH);
    float var = 0.0f;
    #pragma unroll
    for (int h = 0; h < HH; ++h) { float dd = pr[h] - mu; var = fmaf(dd, dd, var); }
    const float rs = rsqrtf(var * (1.0f / HH) + 1e-5f);
    #pragma unroll
    for (int h = 0; h < HH; ++h) pr[h] = fmaf((pr[h] - mu) * rs, lnSL[h], lnOL[h]);

    float4* hrow = (float4*)(&hidL[t][0]);
    #pragma unroll 1
    for (int q = 0; q < 8; ++q) {
        float4 a = make_float4(0.f, 0.f, 0.f, 0.f);
        #pragma unroll
        for (int h = 0; h < HH; ++h) {
            float4 w = Wh4[h*8 + q];
            a.x = fmaf(pr[h], w.x, a.x);
            a.y = fmaf(pr[h], w.y, a.y);
            a.z = fmaf(pr[h], w.z, a.z);
            a.w = fmaf(pr[h], w.w, a.w);
        }
        a.x = gelu_f(a.x); a.y = gelu_f(a.y); a.z = gelu_f(a.z); a.w = gelu_f(a.w);
        hrow[q] = a;
    }
    pmf[t] = pm;
    __syncthreads();

    // ---- phase 2: column-parallel W_out matmul, coalesced float2 stores ----
    const int s2 = t & 31;                      // this thread owns out cols 2*s2, 2*s2+1
    float wa[HH], wb[HH];
    #pragma unroll
    for (int k = 0; k < HH; ++k) {
        float2 w = *(const float2*)(Wout + k*SS + 2*s2);
        wa[k] = w.x; wb[k] = w.y;
    }
    float2* outu = (float2*)(out + ((size_t)i * NN + j0) * SS);
    #pragma unroll 1
    for (int m = 0; m < 32; ++m) {
        const int jj = (t >> 5) + m * 8;
        const float4* hr = (const float4*)(&hidL[jj][0]);
        float hh[HH];
        #pragma unroll
        for (int q = 0; q < 8; ++q) {
            float4 v = hr[q];
            hh[4*q+0] = v.x; hh[4*q+1] = v.y; hh[4*q+2] = v.z; hh[4*q+3] = v.w;
        }
        float oa = 0.0f, ob = 0.0f;
        #pragma unroll
        for (int k = 0; k < HH; ++k) {
            oa = fmaf(hh[k], wa[k], oa);
            ob = fmaf(hh[k], wb[k], ob);
        }
        const float p = pmf[jj];
        oa *= p; ob *= p;
        outu[m*256 + t] = make_float2(oa, ob);
    }
}

extern "C" void kernel_launch(void* const* d_in, const int* in_sizes, int n_in,
                              void* d_out, int out_size, void* d_ws, size_t ws_size,
                              hipStream_t stream)
{
    const float* local_ = (const float*)d_in[0];
    const int* resi  = (const int*)d_in[1];
    const int* chain = (const int*)d_in[2];
    const int* batch = (const int*)d_in[3];
    const int* mask  = (const int*)d_in[4];   // bool input staged as int32
    const float* Wl   = (const float*)d_in[5];
    const float* Wr   = (const float*)d_in[6];
    const float* Wrel = (const float*)d_in[7];
    const float* lnS  = (const float*)d_in[8];
    const float* lnO  = (const float*)d_in[9];
    const float* Wh   = (const float*)d_in[10];
    const float* Wout = (const float*)d_in[11];
    float* out = (float*)d_out;

    float* leftF  = (float*)d_ws;            // 1024*32 fp32
    float* rightF = leftF + NN * HH;         // 1024*32 fp32 (256 KB total)

    proj_kernel<<<dim3(NN), dim3(64), 0, stream>>>(local_, Wl, Wr, leftF, rightF);
    pair_kernel<<<dim3(4, NN), dim3(256), 0, stream>>>(
        leftF, rightF, resi, chain, batch, mask, Wrel, lnS, lnO, Wh, Wout, out);
}

// Round 3
// 311.042 us; speedup vs baseline: 1.2304x; 1.2304x over previous
//
#include <hip/hip_runtime.h>

#define NN 1024
#define DD 256
#define HH 32
#define SS 64

typedef short bf16x8 __attribute__((ext_vector_type(8)));
typedef float f32x4  __attribute__((ext_vector_type(4)));

__device__ __forceinline__ unsigned short f2bf(float f) {
    union { float f; unsigned int i; } v; v.f = f;
    unsigned int r = v.i + 0x7FFFu + ((v.i >> 16) & 1u);  // RNE; no NaN expected
    return (unsigned short)(r >> 16);
}

__device__ __forceinline__ float gelu_f(float x) {
    // jax.nn.gelu approximate=True
    const float c1 = 0.7978845608028654f, c2 = 0.044715f;
    float u = c1 * fmaf(c2 * x * x, x, x);
    float e = __expf(-2.0f * fabsf(u));
    float th = (1.0f - e) / (1.0f + e);
    th = copysignf(th, u);
    return 0.5f * x * (1.0f + th);
}

// left = local @ W_left, right = local @ W_right  (fp32 out to workspace)
__global__ __launch_bounds__(64) void proj_kernel(
    const float* __restrict__ local_,
    const float* __restrict__ Wl,
    const float* __restrict__ Wr,
    float* __restrict__ leftF, float* __restrict__ rightF)
{
    __shared__ float row[DD];
    const int i = blockIdx.x, t = threadIdx.x;
    float4 v = ((const float4*)(local_ + (size_t)i * DD))[t];
    row[4*t+0] = v.x; row[4*t+1] = v.y; row[4*t+2] = v.z; row[4*t+3] = v.w;
    __syncthreads();
    const int h = t & 31;
    const float* W = (t < 32) ? Wl : Wr;
    float acc = 0.0f;
    #pragma unroll 8
    for (int d = 0; d < DD; ++d) acc = fmaf(row[d], W[d*HH + h], acc);
    float* dst = (t < 32) ? leftF : rightF;
    dst[i*HH + h] = acc;
}

__global__ __launch_bounds__(256) void pair_kernel(
    const float* __restrict__ leftF, const float* __restrict__ rightF,
    const int* __restrict__ resi, const int* __restrict__ chain,
    const int* __restrict__ batch, const int* __restrict__ mask,
    const float* __restrict__ Wrel,
    const float* __restrict__ lnS, const float* __restrict__ lnO,
    const float* __restrict__ Wh, const float* __restrict__ Wout,
    float* __restrict__ out)
{
    __shared__ float relL[65 * 36];            // padded rows: 36 f32 (bank-spread)
    __shared__ unsigned short WhT[32 * 32];    // WhT[n][k] = Wh[k][n], bf16
    __shared__ unsigned short WoT[64 * 32];    // WoT[s][k] = Wout[k][s], bf16
    __shared__ unsigned short hidL[4 * 16 * 40]; // per-wave 16 pairs x 40-short rows

    const int tid  = threadIdx.x;
    const int wave = tid >> 6;
    const int lane = tid & 63;
    const int q    = lane >> 4;    // quad 0..3
    const int p    = lane & 15;    // pair-slot 0..15
    const int i    = blockIdx.y;
    const int jb   = blockIdx.x;   // 0..3, each covers 256 j

    // ---- one-time staging ----
    for (int idx = tid; idx < 65 * 32; idx += 256)
        relL[(idx >> 5) * 36 + (idx & 31)] = Wrel[idx];
    for (int idx = tid; idx < 32 * 32; idx += 256) {
        int k = idx >> 5, n = idx & 31;
        WhT[n * 32 + k] = f2bf(Wh[idx]);
    }
    for (int idx = tid; idx < 64 * 32; idx += 256) {
        int k = idx >> 6, s = idx & 63;
        WoT[s * 32 + k] = f2bf(Wout[idx]);
    }
    __syncthreads();

    // ---- block-constant registers ----
    const int bi = batch[i], ci = chain[i], ri = resi[i], mi = mask[i];
    float left8[8], lnS8[8], lnO8[8];
    {
        const float4 l0 = *(const float4*)&leftF[i * HH + 8 * q];
        const float4 l1 = *(const float4*)&leftF[i * HH + 8 * q + 4];
        left8[0]=l0.x; left8[1]=l0.y; left8[2]=l0.z; left8[3]=l0.w;
        left8[4]=l1.x; left8[5]=l1.y; left8[6]=l1.z; left8[7]=l1.w;
        #pragma unroll
        for (int e = 0; e < 8; ++e) { lnS8[e] = lnS[8*q + e]; lnO8[e] = lnO[8*q + e]; }
    }
    const bf16x8 whB0 = *(const bf16x8*)&WhT[(p      ) * 32 + 8 * q];
    const bf16x8 whB1 = *(const bf16x8*)&WhT[(16 + p ) * 32 + 8 * q];
    bf16x8 woB[4];
    #pragma unroll
    for (int t = 0; t < 4; ++t)
        woB[t] = *(const bf16x8*)&WoT[(16 * t + p) * 32 + 8 * q];

    unsigned short* hidw = &hidL[wave * 16 * 40];

    for (int it = 0; it < 4; ++it) {
        const int jbase = jb * 256 + it * 64 + wave * 16;
        const int j = jbase + p;

        const int bj = batch[j], cj = chain[j], rj = resi[j], mj = mask[j];
        const bool sb = (bi == bj);
        const bool sc = sb && (ci == cj);
        const float pm = (sb && (mi != 0) && (mj != 0)) ? 1.0f : 0.0f;

        // ---- build pair vector (A-frag layout: pair p, feats 8q..8q+7) ----
        float pr[8];
        {
            const float4 r0 = *(const float4*)&rightF[(size_t)j * HH + 8 * q];
            const float4 r1 = *(const float4*)&rightF[(size_t)j * HH + 8 * q + 4];
            pr[0]=left8[0]+r0.x; pr[1]=left8[1]+r0.y; pr[2]=left8[2]+r0.z; pr[3]=left8[3]+r0.w;
            pr[4]=left8[4]+r1.x; pr[5]=left8[5]+r1.y; pr[6]=left8[6]+r1.z; pr[7]=left8[7]+r1.w;
        }
        if (sc) {
            int d = ri - rj; d = d < -32 ? -32 : (d > 32 ? 32 : d);
            const float4 e0 = *(const float4*)&relL[(d + 32) * 36 + 8 * q];
            const float4 e1 = *(const float4*)&relL[(d + 32) * 36 + 8 * q + 4];
            pr[0]+=e0.x; pr[1]+=e0.y; pr[2]+=e0.z; pr[3]+=e0.w;
            pr[4]+=e1.x; pr[5]+=e1.y; pr[6]+=e1.z; pr[7]+=e1.w;
        }

        // ---- LayerNorm across the 4 quads holding this pair ----
        float s = 0.0f;
        #pragma unroll
        for (int e = 0; e < 8; ++e) s += pr[e];
        s += __shfl_xor(s, 16, 64);
        s += __shfl_xor(s, 32, 64);
        const float mu = s * (1.0f / HH);
        float v = 0.0f;
        #pragma unroll
        for (int e = 0; e < 8; ++e) { float dd = pr[e] - mu; v = fmaf(dd, dd, v); }
        v += __shfl_xor(v, 16, 64);
        v += __shfl_xor(v, 32, 64);
        const float rs = rsqrtf(v * (1.0f / HH) + 1e-5f);

        bf16x8 aF;
        #pragma unroll
        for (int e = 0; e < 8; ++e)
            aF[e] = (short)f2bf(fmaf((pr[e] - mu) * rs, lnS8[e], lnO8[e]));

        // ---- matmul1: hidden = pairLN @ Wh  (two 16-col tiles) ----
        f32x4 z = {0.f, 0.f, 0.f, 0.f};
        f32x4 h0 = __builtin_amdgcn_mfma_f32_16x16x32_bf16(aF, whB0, z, 0, 0, 0);
        f32x4 h1 = __builtin_amdgcn_mfma_f32_16x16x32_bf16(aF, whB1, z, 0, 0, 0);

        // ---- gelu + C-layout -> A-layout transform through LDS ----
        #pragma unroll
        for (int r = 0; r < 4; ++r) {
            const int pr_row = 4 * q + r;     // pair index (C layout row)
            hidw[pr_row * 40 + p]      = f2bf(gelu_f(h0[r]));
            hidw[pr_row * 40 + p + 16] = f2bf(gelu_f(h1[r]));
        }
        __syncthreads();
        const bf16x8 aH = *(const bf16x8*)&hidw[p * 40 + 8 * q];

        // ---- matmul2: out = hidden @ Wout  (four 16-col tiles) ----
        f32x4 o0 = __builtin_amdgcn_mfma_f32_16x16x32_bf16(aH, woB[0], z, 0, 0, 0);
        f32x4 o1 = __builtin_amdgcn_mfma_f32_16x16x32_bf16(aH, woB[1], z, 0, 0, 0);
        f32x4 o2 = __builtin_amdgcn_mfma_f32_16x16x32_bf16(aH, woB[2], z, 0, 0, 0);
        f32x4 o3 = __builtin_amdgcn_mfma_f32_16x16x32_bf16(aH, woB[3], z, 0, 0, 0);

        // ---- mask + store (C layout: row=pair 4q+r, col=16t+p) ----
        float pmv[4];
        #pragma unroll
        for (int r = 0; r < 4; ++r) pmv[r] = __shfl(pm, 4 * q + r, 64);

        #pragma unroll
        for (int r = 0; r < 4; ++r) {
            float* orow = out + ((size_t)i * NN + (size_t)(jbase + 4 * q + r)) * SS + p;
            orow[ 0] = o0[r] * pmv[r];
            orow[16] = o1[r] * pmv[r];
            orow[32] = o2[r] * pmv[r];
            orow[48] = o3[r] * pmv[r];
        }
        __syncthreads();
    }
}

extern "C" void kernel_launch(void* const* d_in, const int* in_sizes, int n_in,
                              void* d_out, int out_size, void* d_ws, size_t ws_size,
                              hipStream_t stream)
{
    const float* local_ = (const float*)d_in[0];
    const int* resi  = (const int*)d_in[1];
    const int* chain = (const int*)d_in[2];
    const int* batch = (const int*)d_in[3];
    const int* mask  = (const int*)d_in[4];
    const float* Wl   = (const float*)d_in[5];
    const float* Wr   = (const float*)d_in[6];
    const float* Wrel = (const float*)d_in[7];
    const float* lnS  = (const float*)d_in[8];
    const float* lnO  = (const float*)d_in[9];
    const float* Wh   = (const float*)d_in[10];
    const float* Wout = (const float*)d_in[11];
    float* out = (float*)d_out;

    float* leftF  = (float*)d_ws;            // 1024*32 fp32
    float* rightF = leftF + NN * HH;         // 1024*32 fp32

    proj_kernel<<<dim3(NN), dim3(64), 0, stream>>>(local_, Wl, Wr, leftF, rightF);
    pair_kernel<<<dim3(4, NN), dim3(256), 0, stream>>>(
        leftF, rightF, resi, chain, batch, mask, Wrel, lnS, lnO, Wh, Wout, out);
}